// Round 16
// baseline (67.598 us; speedup 1.0000x reference)
//
#include <hip/hip_runtime.h>
#include <stdint.h>

// ---- problem constants ----
#define DHW         13824      // 24*24*24 spatial positions per (b,c,g) plane
#define NCH         32         // channels C
#define NG          24         // octahedral group order
#define KDIM        2304       // ORIGINAL GEMM K (32 ch * 72)
#define NHEAD       64
#define TP          16         // spatial positions per block
#define CHS         8          // channels per stage (4 stages/tile)
#define NSTG        4
#define FPC         64         // folded+padded features/channel (2 x [12 t0 | 6 t1 | 12 t2 | 2 pad])
#define KP2         2048       // folded K: 32 ch x 64
#define KS2         64         // total K-steps (KP2/32)
#define KSTG        16         // K-steps per stage-block (8 ch x 64 / 32)
#define KQ          4          // K-steps per wave (16/4)
#define RPE         512        // LDS row pitch in bf16 elems (8 ch x 64, no pad; XOR chunks)
#define TILES_PER_B 864        // DHW / TP
#define NTILES      1728       // B * TILES_PER_B
#define NB          (NTILES * NSTG)    // 6912 blocks
#define OUTN        1769472    // B * NHEAD * DHW  (output floats)

typedef __attribute__((ext_vector_type(2))) float    f32x2;
typedef __attribute__((ext_vector_type(8))) short    s16x8;
typedef __attribute__((ext_vector_type(4))) float    f32x4;
typedef __attribute__((ext_vector_type(4))) uint32_t u32x4;

// ---- compile-time Cayley table of S4 (matches itertools.permutations order) ----
// t1-fold extras: t1h[h] = t1*h, rep[12] = representatives of tau1[h]==tau1[t1*h].
struct Tables { int cay[NG][NG]; int s1[NG]; int s2[NG]; int t1h[NG]; int rep[12]; };

constexpr Tables make_tables() {
    int perms[NG][4] = {};
    int n = 0;
    for (int a = 0; a < 4; ++a)
        for (int b = 0; b < 4; ++b) {
            if (b == a) continue;
            for (int c = 0; c < 4; ++c) {
                if (c == a || c == b) continue;
                int d = 6 - a - b - c;
                perms[n][0] = a; perms[n][1] = b; perms[n][2] = c; perms[n][3] = d;
                ++n;
            }
        }
    int si1 = 0, si2 = 0;
    for (int i = 0; i < NG; ++i) {
        if (perms[i][0] == 1 && perms[i][1] == 0 && perms[i][2] == 2 && perms[i][3] == 3) si1 = i;
        if (perms[i][0] == 1 && perms[i][1] == 2 && perms[i][2] == 3 && perms[i][3] == 0) si2 = i;
    }
    Tables t{};
    for (int p = 0; p < NG; ++p) {
        for (int q = 0; q < NG; ++q) {
            int c0 = perms[p][perms[q][0]];
            int c1 = perms[p][perms[q][1]];
            int c2 = perms[p][perms[q][2]];
            int c3 = perms[p][perms[q][3]];
            int r = 0;
            for (int i = 0; i < NG; ++i)
                if (perms[i][0] == c0 && perms[i][1] == c1 &&
                    perms[i][2] == c2 && perms[i][3] == c3) { r = i; break; }
            t.cay[p][q] = r;
        }
        t.s1[p] = t.cay[p][si1];
        t.s2[p] = t.cay[p][si2];
    }
    for (int h = 0; h < NG; ++h) t.t1h[h] = t.cay[si1][h];   // t1 o h
    int nr = 0;
    for (int h = 0; h < NG; ++h) if (h < t.t1h[h]) t.rep[nr++] = h;   // 12 pairs
    return t;
}
constexpr Tables TAB = make_tables();

__device__ __forceinline__ uint32_t f2bf(float f) {   // fp32 -> bf16 (RNE), u16 in low bits
    uint32_t u = __float_as_uint(f);
    u += 0x7fffu + ((u >> 16) & 1u);
    return u >> 16;
}

// ---- kernel 1: fold + swizzle W into the HALF-GROUPED folded feature order.
// Per channel, f in [0,64): half H = f>>5, fl = f&31:
//   fl in [0,12):  tau0[H*12+fl] | [12,18): tau1[rep[H*6+fl-12]] pair-summed |
//   [18,30): tau2[H*12+fl-18]    | [30,32): zero pad.
// ln2 folded in (phase A uses log2). WbS[((ot*KS2+kk)*64+lane)*8+j] as before.
__global__ __launch_bounds__(256) void prep_w(const float* __restrict__ W,
                                              unsigned short* __restrict__ WbS) {
    int i = blockIdx.x * 256 + threadIdx.x;      // < 64*2048 = 131072
    int j  = i & 7;
    int t1_ = i >> 3;
    int l  = t1_ & 63;
    int t2_ = t1_ >> 6;
    int kk = t2_ & (KS2 - 1);
    int ot = t2_ >> 6;
    int o = ot * 16 + (l & 15);
    int k = kk * 32 + ((l >> 4) << 3) + j;       // 0..2047 folded-K column
    int c  = k >> 6;                             // channel 0..31
    int f  = k & 63;
    int H  = f >> 5, fl = f & 31;
    const float* Wo = W + o * KDIM + c * 72;
    float val = 0.f;
    if (fl < 12)      val = Wo[(H * 12 + fl) * 3 + 0];
    else if (fl < 18) { int h = TAB.rep[H * 6 + fl - 12];
                        val = Wo[h * 3 + 1] + Wo[TAB.t1h[h] * 3 + 1]; }
    else if (fl < 30) val = Wo[(H * 12 + fl - 18) * 3 + 2];
    WbS[i] = (unsigned short)f2bf(val * 0.69314718055994531f);
}

// ---- kernel 3: in-place bias add on the atomically-accumulated output ----
__global__ __launch_bounds__(256) void bias_add(float* __restrict__ y,
                                                const float* __restrict__ bias) {
    const int i4 = blockIdx.x * 256 + threadIdx.x;      // float4 index
    f32x4 v = ((f32x4*)y)[i4];
    const float b = bias[((i4 * 4) / DHW) & (NHEAD - 1)];
    v[0] += b; v[1] += b; v[2] += b; v[3] += b;
    ((f32x4*)y)[i4] = v;
}

// tau-core for one h-half: H compile-time so every xf[] index is static (R12 mechanism).
template<int H>
__device__ __forceinline__ void half_core(const float (&xf)[NG],
                                          f32x2 (&tau02)[12], float (&tau1)[6]) {
    #pragma unroll
    for (int i = 0; i < 12; ++i) tau02[i] = (f32x2){0.f, 0.f};
    #pragma unroll
    for (int i = 0; i < 6; ++i) tau1[i] = 0.f;
    #pragma unroll
    for (int g = 0; g < NG; ++g) {
        const float xg = xf[g];
        const f32x2 q02 = (f32x2){xg, xg} * (f32x2){xg, xf[TAB.s2[g]]};
        const float q1 = xg * xf[TAB.s1[g]];
        #pragma unroll
        for (int hh = 0; hh < 12; ++hh) {
            const float v = xf[TAB.cay[g][H * 12 + hh]];
            tau02[hh] = __builtin_elementwise_fma((f32x2){v, v}, q02, tau02[hh]);
        }
        #pragma unroll
        for (int rr = 0; rr < 6; ++rr) {
            const float v = xf[TAB.cay[g][TAB.rep[H * 6 + rr]]];
            tau1[rr] = fmaf(q1, v, tau1[rr]);
        }
    }
}

// ---- kernel 2: quarter-stage fused kernel. Each block = (tile, 8-ch stage); grid 6912.
// 256 threads (4 waves) = 16 pos x 8 ch x 2 h-halves: per-thread live state ~54 regs
// (24 xf + 12 f32x2 + 6) -> honestly fits the 64-VGPR allocation without compiler
// loop-splitting (R15 post-mortem: 84-live at VGPR=64 implied hidden recompute).
// launch_bounds(256,2): the only healthy allocator surface (R7-R15 evidence).
// Phase B: K-split across waves (R13), 4 steps/wave, XOR chunk swizzle (R15).
// Output: atomicAdd into pre-zeroed d_out (4 commutative adds/elem; R12-proven).
__global__ __launch_bounds__(256, 2)
void bispec_fused(
        const float* __restrict__ x,
        const unsigned short* __restrict__ WbS,
        float* __restrict__ y)            // d_out, pre-zeroed; bias added later
{
    __shared__ alignas(16) unsigned short featS[TP * RPE];   // 16,384 B

    const int bid = blockIdx.x;
    // XCD-chunked swizzle (NB % 8 == 0); tile-major within chunk
    const int swz  = (bid & 7) * (NB / 8) + (bid >> 3);
    const int tile = swz >> 2;           // 0..1727
    const int cs   = swz & 3;            // 8-channel stage 0..3
    const int bb  = tile / TILES_PER_B;
    const int psp = (tile - bb * TILES_PER_B) * TP;
    const int tid = threadIdx.x;

    const int p0 = tid & 15;             // position (phase A)
    const int cl = (tid >> 4) & 7;       // local channel 0..7 (phase A)
    const int H  = tid >> 7;             // h-half 0/1 == wave pair (uniform per wave)
    const int w  = tid >> 6;             // wave: k-quarter in B, o-tile in epilogue
    const int l  = tid & 63;
    const int ln = l & 15;               // position col (phase B)
    const int lh = l >> 4;               // k sub-block (phase B)

    // ---------------- phase A: half (c,p) row per thread ----------------
    {
        const int c0 = cs * CHS + cl;
        // 32-bit divergent index vs uniform base -> saddr-form global_load_dword
        const unsigned idx0 = (unsigned)(bb * NCH + c0) * (NG * DHW) + (unsigned)(psp + p0);
        float xf[NG];
        #pragma unroll
        for (int g = 0; g < NG; ++g) xf[g] = x[idx0 + (unsigned)(g * DHW)];

        f32x2 tau02[12];
        float tau1[6];
        if (tid < 128) half_core<0>(xf, tau02, tau1);
        else           half_core<1>(xf, tau02, tau1);

        // feature = log2(1 + max(tau,0))  [ln2 folded into W; log2(1)=0 exact]
        uint32_t pk[16];
        #pragma unroll
        for (int i = 0; i < 6; ++i) {         // fl 0..11: tau0
            float a = __log2f(1.f + fmaxf(tau02[2*i][0],   0.f));
            float b = __log2f(1.f + fmaxf(tau02[2*i+1][0], 0.f));
            pk[i] = f2bf(a) | (f2bf(b) << 16);
        }
        #pragma unroll
        for (int i = 0; i < 3; ++i) {         // fl 12..17: tau1 reps
            float a = __log2f(1.f + fmaxf(tau1[2*i],   0.f));
            float b = __log2f(1.f + fmaxf(tau1[2*i+1], 0.f));
            pk[6 + i] = f2bf(a) | (f2bf(b) << 16);
        }
        #pragma unroll
        for (int i = 0; i < 6; ++i) {         // fl 18..29: tau2
            float a = __log2f(1.f + fmaxf(tau02[2*i][1],   0.f));
            float b = __log2f(1.f + fmaxf(tau02[2*i+1][1], 0.f));
            pk[9 + i] = f2bf(a) | (f2bf(b) << 16);
        }
        pk[15] = 0u;                          // fl 30..31: pad (W' columns zero)
        // write 4 x 16B chunks; physical chunk = (cl*8 + H*4 + j) ^ (p0&7)
        uint32_t* rowb = (uint32_t*)featS + p0 * (RPE / 2);   // 256 dwords/row
        const int cb = cl * 8 + H * 4;
        #pragma unroll
        for (int j = 0; j < 4; ++j) {
            u32x4 v; v[0] = pk[j*4]; v[1] = pk[j*4+1]; v[2] = pk[j*4+2]; v[3] = pk[j*4+3];
            *(u32x4*)(rowb + (((cb + j) ^ (p0 & 7)) << 2)) = v;
        }
    }
    __syncthreads();

    // ---- phase B: wave w accumulates k-steps [4w, 4w+4) for ALL 4 o-tiles ----
    f32x4 accA = {0.f, 0.f, 0.f, 0.f};
    f32x4 accB = {0.f, 0.f, 0.f, 0.f};
    f32x4 accC = {0.f, 0.f, 0.f, 0.f};
    f32x4 accD = {0.f, 0.f, 0.f, 0.f};
    {
        const unsigned kb = (unsigned)(cs * KSTG + w * KQ);   // global k-step
        const unsigned short* rowr = featS + ln * RPE;
        const int sx = ln & 7;
        const s16x8* wb = (const s16x8*)WbS;

        // logical chunk for (kk, lh): w*16 + kk*4 + lh; physical = ^ sx
        s16x8 bc = *(const s16x8*)(rowr + (((w * 16 + lh) ^ sx) << 3));
        #pragma unroll
        for (int kk = 0; kk < KQ; ++kk) {
            s16x8 bn = bc;
            if (kk + 1 < KQ)
                bn = *(const s16x8*)(rowr + (((w * 16 + (kk + 1) * 4 + lh) ^ sx) << 3));
            const unsigned ai = (kb + (unsigned)kk) * 64u + (unsigned)l;
            s16x8 a0 = wb[ai];
            s16x8 a1 = wb[ai + 1u * KS2 * 64u];
            s16x8 a2 = wb[ai + 2u * KS2 * 64u];
            s16x8 a3 = wb[ai + 3u * KS2 * 64u];
            accA = __builtin_amdgcn_mfma_f32_16x16x32_bf16(a0, bc, accA, 0, 0, 0);
            accB = __builtin_amdgcn_mfma_f32_16x16x32_bf16(a1, bc, accB, 0, 0, 0);
            accC = __builtin_amdgcn_mfma_f32_16x16x32_bf16(a2, bc, accC, 0, 0, 0);
            accD = __builtin_amdgcn_mfma_f32_16x16x32_bf16(a3, bc, accD, 0, 0, 0);
            bc = bn;
        }
    }
    __syncthreads();   // all ds_reads done before redS overlay

    // ---- epilogue: cross-wave k-reduction (featS dead -> overlay), atomic o-tile w ----
    f32x4* redS = (f32x4*)featS;      // 4 waves x 4 o-tiles x 64 lanes x 16B = 16,384 B
    redS[(w * 4 + 0) * 64 + l] = accA;
    redS[(w * 4 + 1) * 64 + l] = accB;
    redS[(w * 4 + 2) * 64 + l] = accC;
    redS[(w * 4 + 3) * 64 + l] = accD;
    __syncthreads();
    f32x4 r = redS[(0 * 4 + w) * 64 + l] + redS[(1 * 4 + w) * 64 + l]
            + redS[(2 * 4 + w) * 64 + l] + redS[(3 * 4 + w) * 64 + l];

    // D layout: col = lane&15 (position), row = (lane>>4)*4 + j (head within o-tile w)
    const size_t obase = (size_t)bb * NHEAD * DHW + (size_t)(psp + ln);
    #pragma unroll
    for (int j = 0; j < 4; ++j) {
        const int o = w * 16 + lh * 4 + j;
        atomicAdd(&y[obase + (size_t)o * DHW], r[j]);
    }
}

extern "C" void kernel_launch(void* const* d_in, const int* in_sizes, int n_in,
                              void* d_out, int out_size, void* d_ws, size_t ws_size,
                              hipStream_t stream) {
    const float* x    = (const float*)d_in[0];
    const float* W    = (const float*)d_in[1];
    const float* bias = (const float*)d_in[2];
    unsigned short* WbS = (unsigned short*)d_ws;            // 262,144 B used
    float* y = (float*)d_out;

    prep_w<<<dim3(NHEAD * KP2 / 256), dim3(256), 0, stream>>>(W, WbS);
    hipMemsetAsync(y, 0, (size_t)OUTN * sizeof(float), stream);
    bispec_fused<<<dim3(NB), dim3(256), 0, stream>>>(x, WbS, y);
    bias_add<<<dim3(OUTN / 4 / 256), dim3(256), 0, stream>>>(y, bias);
}

// Round 17
// 60.213 us; speedup vs baseline: 1.1226x; 1.1226x over previous
//
#include <hip/hip_runtime.h>
#include <stdint.h>

// ---- problem constants ----
#define DHW         13824      // 24*24*24 spatial positions per (b,c,g) plane
#define NCH         32         // channels C
#define NG          24         // octahedral group order
#define KDIM        2304       // ORIGINAL GEMM K (32 ch * 72)
#define NHEAD       64
#define TP          16         // spatial positions per block
#define CHS         16         // channels per stage (2 stages)
#define FPC         64         // folded+padded features/channel (60 distinct + 4 pad)
#define KP2         2048       // padded folded K: 2 stages x 16 ch x 64
#define KS2         64         // padded K-steps total (KP2/32)
#define KPSTG       32         // K-steps per stage
#define KQ          8          // K-steps per wave per stage (32/4, exact)
#define KPE         1032       // LDS row pitch in bf16 elems (16*64 + 8 pad -> 4-bank skew)
#define TILES_PER_B 864        // DHW / TP
#define NTILES      1728       // B * TILES_PER_B
#define OUTN        1769472    // B * NHEAD * DHW  (output floats)

typedef __attribute__((ext_vector_type(2))) float    f32x2;
typedef __attribute__((ext_vector_type(8))) short    s16x8;
typedef __attribute__((ext_vector_type(4))) float    f32x4;
typedef __attribute__((ext_vector_type(4))) uint32_t u32x4;

// ---- compile-time Cayley table of S4 (matches itertools.permutations order) ----
// t1-fold extras: t1h[h] = t1*h, rep[12] = representatives of tau1[h]==tau1[t1*h].
struct Tables { int cay[NG][NG]; int s1[NG]; int s2[NG]; int t1h[NG]; int rep[12]; };

constexpr Tables make_tables() {
    int perms[NG][4] = {};
    int n = 0;
    for (int a = 0; a < 4; ++a)
        for (int b = 0; b < 4; ++b) {
            if (b == a) continue;
            for (int c = 0; c < 4; ++c) {
                if (c == a || c == b) continue;
                int d = 6 - a - b - c;
                perms[n][0] = a; perms[n][1] = b; perms[n][2] = c; perms[n][3] = d;
                ++n;
            }
        }
    int si1 = 0, si2 = 0;
    for (int i = 0; i < NG; ++i) {
        if (perms[i][0] == 1 && perms[i][1] == 0 && perms[i][2] == 2 && perms[i][3] == 3) si1 = i;
        if (perms[i][0] == 1 && perms[i][1] == 2 && perms[i][2] == 3 && perms[i][3] == 0) si2 = i;
    }
    Tables t{};
    for (int p = 0; p < NG; ++p) {
        for (int q = 0; q < NG; ++q) {
            int c0 = perms[p][perms[q][0]];
            int c1 = perms[p][perms[q][1]];
            int c2 = perms[p][perms[q][2]];
            int c3 = perms[p][perms[q][3]];
            int r = 0;
            for (int i = 0; i < NG; ++i)
                if (perms[i][0] == c0 && perms[i][1] == c1 &&
                    perms[i][2] == c2 && perms[i][3] == c3) { r = i; break; }
            t.cay[p][q] = r;
        }
        t.s1[p] = t.cay[p][si1];
        t.s2[p] = t.cay[p][si2];
    }
    for (int h = 0; h < NG; ++h) t.t1h[h] = t.cay[si1][h];   // t1 o h
    int nr = 0;
    for (int h = 0; h < NG; ++h) if (h < t.t1h[h]) t.rep[nr++] = h;   // 12 pairs
    return t;
}
constexpr Tables TAB = make_tables();

__device__ __forceinline__ uint32_t f2bf(float f) {   // fp32 -> bf16 (RNE), u16 in low bits
    uint32_t u = __float_as_uint(f);
    u += 0x7fffu + ((u >> 16) & 1u);
    return u >> 16;
}

// ---- kernel 1: fold + swizzle W (R14). Folded feature order per channel:
// [0,24): tau0 | [24,36): tau1 reps (pair-summed W) | [36,60): tau2 | [60,64): zero pad.
// ln2 folded in (phase A uses log2).
__global__ __launch_bounds__(256) void prep_w(const float* __restrict__ W,
                                              unsigned short* __restrict__ WbS) {
    int i = blockIdx.x * 256 + threadIdx.x;      // < 64*2048 = 131072
    int j  = i & 7;
    int t1_ = i >> 3;
    int l  = t1_ & 63;
    int t2_ = t1_ >> 6;
    int kk = t2_ & (KS2 - 1);
    int ot = t2_ >> 6;
    int o = ot * 16 + (l & 15);
    int k = kk * 32 + ((l >> 4) << 3) + j;       // 0..2047 folded-K column
    int stage = k >> 10;                         // 0..1
    int q     = k & 1023;
    int c = stage * CHS + (q >> 6);              // channel
    int f = q & 63;                              // folded feature index
    const float* Wo = W + o * KDIM + c * 72;
    float val = 0.f;
    if (f < 24)      val = Wo[f * 3 + 0];
    else if (f < 36) { int h = TAB.rep[f - 24]; val = Wo[h * 3 + 1] + Wo[TAB.t1h[h] * 3 + 1]; }
    else if (f < 60) { int h = f - 36;          val = Wo[h * 3 + 2]; }
    WbS[i] = (unsigned short)f2bf(val * 0.69314718055994531f);
}

// ---- kernel 0: pre-fill y with the bias pattern (deterministic full coverage) ----
__global__ __launch_bounds__(256) void bias_fill(float* __restrict__ y,
                                                 const float* __restrict__ bias) {
    const int i4 = blockIdx.x * 256 + threadIdx.x;      // float4 index, OUTN%1024==0
    const float b = bias[((i4 * 4) / DHW) & (NHEAD - 1)];
    f32x4 v; v[0] = b; v[1] = b; v[2] = b; v[3] = b;
    ((f32x4*)y)[i4] = v;
}

// ---- kernel 2: fused bispectrum + log-feature + 64-head GEMM, 16 positions/block.
// EXACTLY R14's proven structure (61.9 us): 256 threads (4 waves), launch_bounds(256,2)
// (the only healthy allocator surface, R7-R16 evidence), one (tile, 16-ch stage) per
// block (grid 3456), t1-folded K=2048, K-split phase B (R13), padded-KPE LDS layout.
// R17 change: epilogue atomicAdds the k-reduced partials straight into bias-prefilled
// y (2 commutative fp32 adds/elem, R12/R16-proven) -- removes the partial-plane
// round-trip (13.8 MB write + 13.8 read + 6.9 write) and the reduce_y dispatch.
__global__ __launch_bounds__(256, 2)
void bispec_fused(
        const float* __restrict__ x,
        const unsigned short* __restrict__ WbS,
        float* __restrict__ y)            // bias-prefilled output, atomic accumulate
{
    __shared__ alignas(16) unsigned short featS[TP * KPE];   // 33,024 B

    const int bid = blockIdx.x;
    const int NB  = NTILES * 2;
    // XCD-chunked swizzle (NB % 8 == 0); bijection bid -> (tile, stage)
    const int swz   = (bid & 7) * (NB / 8) + (bid >> 3);
    const int tile  = swz % NTILES;
    const int stage = swz / NTILES;
    const int bb  = tile / TILES_PER_B;
    const int psp = (tile - bb * TILES_PER_B) * TP;
    const int tid = threadIdx.x;

    const int p0 = tid & 15;          // position within tile (phase A)
    const int cl = tid >> 4;          // local channel 0..15 (phase A)
    const int w  = tid >> 6;          // wave: k-quarter in phase B, o-tile in epilogue
    const int l  = tid & 63;
    const int ln = l & 15;            // position col (phase B)
    const int lh = l >> 4;            // k sub-block (phase B)

    f32x4 accA = {0.f, 0.f, 0.f, 0.f};   // o-tile 0 (heads  0..15)
    f32x4 accB = {0.f, 0.f, 0.f, 0.f};   // o-tile 1 (heads 16..31)
    f32x4 accC = {0.f, 0.f, 0.f, 0.f};   // o-tile 2 (heads 32..47)
    f32x4 accD = {0.f, 0.f, 0.f, 0.f};   // o-tile 3 (heads 48..63)

    // ---------------- phase A: one full (c,p) row per thread ----------------
    {
        const int c0 = stage * CHS + cl;
        // 32-bit divergent index vs uniform base -> saddr-form global_load_dword
        const unsigned idx0 = (unsigned)(bb * NCH + c0) * (NG * DHW) + (unsigned)(psp + p0);
        float xf[NG];
        #pragma unroll
        for (int g = 0; g < NG; ++g) xf[g] = x[idx0 + (unsigned)(g * DHW)];

        f32x2 tau02[NG];         // (tau0, tau2) packed
        float tau1[12];          // 12 distinct s1 values (t1-fold)
        #pragma unroll
        for (int h = 0; h < NG; ++h) tau02[h] = (f32x2){0.f, 0.f};
        #pragma unroll
        for (int r = 0; r < 12; ++r) tau1[r] = 0.f;
        #pragma unroll
        for (int g = 0; g < NG; ++g) {
            const float xg = xf[g];
            const f32x2 q02 = (f32x2){xg, xg} * (f32x2){xg, xf[TAB.s2[g]]};
            const float q1 = xg * xf[TAB.s1[g]];
            #pragma unroll
            for (int h = 0; h < NG; ++h) {
                const float v = xf[TAB.cay[g][h]];   // static register index
                tau02[h] = __builtin_elementwise_fma((f32x2){v, v}, q02, tau02[h]);
            }
            #pragma unroll
            for (int r = 0; r < 12; ++r) {
                const float v = xf[TAB.cay[g][TAB.rep[r]]];   // static register index
                tau1[r] = fmaf(q1, v, tau1[r]);
            }
        }
        // feature = log2(1 + max(tau,0))  [ln2 folded into W; log2(1)=0 exact]
        uint32_t pk[FPC / 2];
        #pragma unroll
        for (int i = 0; i < 12; ++i) {        // f 0..23: tau0
            float a = __log2f(1.f + fmaxf(tau02[2*i][0],   0.f));
            float b = __log2f(1.f + fmaxf(tau02[2*i+1][0], 0.f));
            pk[i] = f2bf(a) | (f2bf(b) << 16);
        }
        #pragma unroll
        for (int i = 0; i < 6; ++i) {         // f 24..35: tau1 reps
            float a = __log2f(1.f + fmaxf(tau1[2*i],   0.f));
            float b = __log2f(1.f + fmaxf(tau1[2*i+1], 0.f));
            pk[12 + i] = f2bf(a) | (f2bf(b) << 16);
        }
        #pragma unroll
        for (int i = 0; i < 12; ++i) {        // f 36..59: tau2
            float a = __log2f(1.f + fmaxf(tau02[2*i][1],   0.f));
            float b = __log2f(1.f + fmaxf(tau02[2*i+1][1], 0.f));
            pk[18 + i] = f2bf(a) | (f2bf(b) << 16);
        }
        pk[30] = 0u; pk[31] = 0u;             // f 60..63: pad (W' columns are zero)
        // row: p0*2064B (16B-aligned) + cl*128B (16B-aligned) -> 8 x b128 stores
        uint32_t* dst = (uint32_t*)&featS[p0 * KPE + cl * FPC];
        #pragma unroll
        for (int i = 0; i < FPC / 2; i += 4) {
            u32x4 v; v[0] = pk[i]; v[1] = pk[i+1]; v[2] = pk[i+2]; v[3] = pk[i+3];
            *(u32x4*)(dst + i) = v;
        }
    }
    __syncthreads();

    // ---- phase B: wave w accumulates k-steps [8w, 8w+8) for ALL 4 o-tiles ----
    {
        const unsigned kb = (unsigned)(stage * KPSTG + w * KQ);   // global k-step
        const unsigned short* fb = &featS[ln * KPE + (w * KQ) * 32 + lh * 8];
        const s16x8* wb = (const s16x8*)WbS;

        s16x8 bc = *(const s16x8*)(fb);          // b prefetch (shared by 4 o-tiles)
        #pragma unroll
        for (int kk = 0; kk < KQ; ++kk) {
            s16x8 bn = bc;
            if (kk + 1 < KQ) bn = *(const s16x8*)(fb + (kk + 1) * 32);
            const unsigned ai = (kb + (unsigned)kk) * 64u + (unsigned)l;
            s16x8 a0 = wb[ai];
            s16x8 a1 = wb[ai + 1u * KS2 * 64u];
            s16x8 a2 = wb[ai + 2u * KS2 * 64u];
            s16x8 a3 = wb[ai + 3u * KS2 * 64u];
            accA = __builtin_amdgcn_mfma_f32_16x16x32_bf16(a0, bc, accA, 0, 0, 0);
            accB = __builtin_amdgcn_mfma_f32_16x16x32_bf16(a1, bc, accB, 0, 0, 0);
            accC = __builtin_amdgcn_mfma_f32_16x16x32_bf16(a2, bc, accC, 0, 0, 0);
            accD = __builtin_amdgcn_mfma_f32_16x16x32_bf16(a3, bc, accD, 0, 0, 0);
            bc = bn;
        }
    }
    __syncthreads();   // all ds_reads done before redS overlay

    // ---- epilogue: cross-wave k-reduction (featS dead -> overlay), atomic o-tile w ----
    f32x4* redS = (f32x4*)featS;      // 4 waves x 4 o-tiles x 64 lanes x 16B = 16 KB
    redS[(w * 4 + 0) * 64 + l] = accA;
    redS[(w * 4 + 1) * 64 + l] = accB;
    redS[(w * 4 + 2) * 64 + l] = accC;
    redS[(w * 4 + 3) * 64 + l] = accD;
    __syncthreads();
    f32x4 r = redS[(0 * 4 + w) * 64 + l] + redS[(1 * 4 + w) * 64 + l]
            + redS[(2 * 4 + w) * 64 + l] + redS[(3 * 4 + w) * 64 + l];

    // D layout: col = lane&15 (position), row = (lane>>4)*4 + j (head within o-tile w)
    const size_t obase = (size_t)bb * NHEAD * DHW + (size_t)(psp + ln);
    #pragma unroll
    for (int j = 0; j < 4; ++j) {
        const int o = w * 16 + lh * 4 + j;
        atomicAdd(&y[obase + (size_t)o * DHW], r[j]);
    }
}

extern "C" void kernel_launch(void* const* d_in, const int* in_sizes, int n_in,
                              void* d_out, int out_size, void* d_ws, size_t ws_size,
                              hipStream_t stream) {
    const float* x    = (const float*)d_in[0];
    const float* W    = (const float*)d_in[1];
    const float* bias = (const float*)d_in[2];
    unsigned short* WbS = (unsigned short*)d_ws;            // 262,144 B used
    float* y = (float*)d_out;

    prep_w<<<dim3(NHEAD * KP2 / 256), dim3(256), 0, stream>>>(W, WbS);
    bias_fill<<<dim3(OUTN / 4 / 256), dim3(256), 0, stream>>>(y, bias);
    bispec_fused<<<dim3(NTILES * 2), dim3(256), 0, stream>>>(x, WbS, y);
}

// Round 18
// 57.841 us; speedup vs baseline: 1.1687x; 1.0410x over previous
//
#include <hip/hip_runtime.h>
#include <stdint.h>

// ---- problem constants ----
#define DHW         13824      // 24*24*24 spatial positions per (b,c,g) plane
#define NCH         32         // channels C
#define NG          24         // octahedral group order
#define KDIM        2304       // ORIGINAL GEMM K (32 ch * 72)
#define NHEAD       64
#define TP          16         // spatial positions per block
#define CHS         16         // channels per stage (2 stages)
#define FPC         64         // folded+padded features/channel (60 distinct + 4 pad)
#define KP2         2048       // padded folded K: 2 stages x 16 ch x 64
#define KS2         64         // padded K-steps total (KP2/32)
#define KPSTG       32         // K-steps per stage
#define KQ          8          // K-steps per wave per stage (32/4, exact)
#define KPE         1032       // LDS row pitch in bf16 elems (16*64 + 8 pad -> 4-bank skew)
#define TILES_PER_B 864        // DHW / TP
#define NTILES      1728       // B * TILES_PER_B
#define OUTN        1769472    // B * NHEAD * DHW  (output floats)
#define PREPB       512        // init_all blocks doing prep_w work (131072/256)
#define FILLB       1728       // init_all blocks doing bias_fill work (OUTN/4/256)

typedef __attribute__((ext_vector_type(2))) float    f32x2;
typedef __attribute__((ext_vector_type(8))) short    s16x8;
typedef __attribute__((ext_vector_type(4))) float    f32x4;
typedef __attribute__((ext_vector_type(4))) uint32_t u32x4;

// ---- compile-time Cayley table of S4 (matches itertools.permutations order) ----
// t1-fold extras: t1h[h] = t1*h, rep[12] = representatives of tau1[h]==tau1[t1*h].
struct Tables { int cay[NG][NG]; int s1[NG]; int s2[NG]; int t1h[NG]; int rep[12]; };

constexpr Tables make_tables() {
    int perms[NG][4] = {};
    int n = 0;
    for (int a = 0; a < 4; ++a)
        for (int b = 0; b < 4; ++b) {
            if (b == a) continue;
            for (int c = 0; c < 4; ++c) {
                if (c == a || c == b) continue;
                int d = 6 - a - b - c;
                perms[n][0] = a; perms[n][1] = b; perms[n][2] = c; perms[n][3] = d;
                ++n;
            }
        }
    int si1 = 0, si2 = 0;
    for (int i = 0; i < NG; ++i) {
        if (perms[i][0] == 1 && perms[i][1] == 0 && perms[i][2] == 2 && perms[i][3] == 3) si1 = i;
        if (perms[i][0] == 1 && perms[i][1] == 2 && perms[i][2] == 3 && perms[i][3] == 0) si2 = i;
    }
    Tables t{};
    for (int p = 0; p < NG; ++p) {
        for (int q = 0; q < NG; ++q) {
            int c0 = perms[p][perms[q][0]];
            int c1 = perms[p][perms[q][1]];
            int c2 = perms[p][perms[q][2]];
            int c3 = perms[p][perms[q][3]];
            int r = 0;
            for (int i = 0; i < NG; ++i)
                if (perms[i][0] == c0 && perms[i][1] == c1 &&
                    perms[i][2] == c2 && perms[i][3] == c3) { r = i; break; }
            t.cay[p][q] = r;
        }
        t.s1[p] = t.cay[p][si1];
        t.s2[p] = t.cay[p][si2];
    }
    for (int h = 0; h < NG; ++h) t.t1h[h] = t.cay[si1][h];   // t1 o h
    int nr = 0;
    for (int h = 0; h < NG; ++h) if (h < t.t1h[h]) t.rep[nr++] = h;   // 12 pairs
    return t;
}
constexpr Tables TAB = make_tables();

__device__ __forceinline__ uint32_t f2bf(float f) {   // fp32 -> bf16 (RNE), u16 in low bits
    uint32_t u = __float_as_uint(f);
    u += 0x7fffu + ((u >> 16) & 1u);
    return u >> 16;
}

// ---- kernel 1: merged init -- blocks [0,PREPB) fold+swizzle W; blocks [PREPB,..)
// pre-fill y with the bias pattern. The two jobs are independent (different in/out);
// merging removes one dispatch boundary (R18: last positive-EV lever; main kernel at
// its converged structure). Branch is block-uniform -> no divergence.
// Folded feature order per channel: [0,24): tau0 | [24,36): tau1 reps (pair-summed W) |
// [36,60): tau2 | [60,64): zero pad. ln2 folded in (phase A uses log2).
__global__ __launch_bounds__(256) void init_all(const float* __restrict__ W,
                                                unsigned short* __restrict__ WbS,
                                                const float* __restrict__ bias,
                                                float* __restrict__ y) {
    const int blk = blockIdx.x;
    if (blk < PREPB) {
        int i = blk * 256 + threadIdx.x;             // < 64*2048 = 131072
        int j  = i & 7;
        int t1_ = i >> 3;
        int l  = t1_ & 63;
        int t2_ = t1_ >> 6;
        int kk = t2_ & (KS2 - 1);
        int ot = t2_ >> 6;
        int o = ot * 16 + (l & 15);
        int k = kk * 32 + ((l >> 4) << 3) + j;       // 0..2047 folded-K column
        int stage = k >> 10;                         // 0..1
        int q     = k & 1023;
        int c = stage * CHS + (q >> 6);              // channel
        int f = q & 63;                              // folded feature index
        const float* Wo = W + o * KDIM + c * 72;
        float val = 0.f;
        if (f < 24)      val = Wo[f * 3 + 0];
        else if (f < 36) { int h = TAB.rep[f - 24];
                           val = Wo[h * 3 + 1] + Wo[TAB.t1h[h] * 3 + 1]; }
        else if (f < 60) { int h = f - 36;          val = Wo[h * 3 + 2]; }
        WbS[i] = (unsigned short)f2bf(val * 0.69314718055994531f);
    } else {
        const int i4 = (blk - PREPB) * 256 + threadIdx.x;   // float4 index, OUTN%1024==0
        const float b = bias[((i4 * 4) / DHW) & (NHEAD - 1)];
        f32x4 v; v[0] = b; v[1] = b; v[2] = b; v[3] = b;
        ((f32x4*)y)[i4] = v;
    }
}

// ---- kernel 2: fused bispectrum + log-feature + 64-head GEMM, 16 positions/block.
// R17's proven structure, UNCHANGED (60.2 us): 256 threads (4 waves),
// launch_bounds(256,2) (the only healthy allocator surface, R7-R16 evidence), one
// (tile, 16-ch stage) per block (grid 3456), t1-folded K=2048, K-split phase B (R13),
// padded-KPE LDS, direct atomicAdd into bias-prefilled y (R17).
__global__ __launch_bounds__(256, 2)
void bispec_fused(
        const float* __restrict__ x,
        const unsigned short* __restrict__ WbS,
        float* __restrict__ y)            // bias-prefilled output, atomic accumulate
{
    __shared__ alignas(16) unsigned short featS[TP * KPE];   // 33,024 B

    const int bid = blockIdx.x;
    const int NB  = NTILES * 2;
    // XCD-chunked swizzle (NB % 8 == 0); bijection bid -> (tile, stage)
    const int swz   = (bid & 7) * (NB / 8) + (bid >> 3);
    const int tile  = swz % NTILES;
    const int stage = swz / NTILES;
    const int bb  = tile / TILES_PER_B;
    const int psp = (tile - bb * TILES_PER_B) * TP;
    const int tid = threadIdx.x;

    const int p0 = tid & 15;          // position within tile (phase A)
    const int cl = tid >> 4;          // local channel 0..15 (phase A)
    const int w  = tid >> 6;          // wave: k-quarter in phase B, o-tile in epilogue
    const int l  = tid & 63;
    const int ln = l & 15;            // position col (phase B)
    const int lh = l >> 4;            // k sub-block (phase B)

    f32x4 accA = {0.f, 0.f, 0.f, 0.f};   // o-tile 0 (heads  0..15)
    f32x4 accB = {0.f, 0.f, 0.f, 0.f};   // o-tile 1 (heads 16..31)
    f32x4 accC = {0.f, 0.f, 0.f, 0.f};   // o-tile 2 (heads 32..47)
    f32x4 accD = {0.f, 0.f, 0.f, 0.f};   // o-tile 3 (heads 48..63)

    // ---------------- phase A: one full (c,p) row per thread ----------------
    {
        const int c0 = stage * CHS + cl;
        // 32-bit divergent index vs uniform base -> saddr-form global_load_dword
        const unsigned idx0 = (unsigned)(bb * NCH + c0) * (NG * DHW) + (unsigned)(psp + p0);
        float xf[NG];
        #pragma unroll
        for (int g = 0; g < NG; ++g) xf[g] = x[idx0 + (unsigned)(g * DHW)];

        f32x2 tau02[NG];         // (tau0, tau2) packed
        float tau1[12];          // 12 distinct s1 values (t1-fold)
        #pragma unroll
        for (int h = 0; h < NG; ++h) tau02[h] = (f32x2){0.f, 0.f};
        #pragma unroll
        for (int r = 0; r < 12; ++r) tau1[r] = 0.f;
        #pragma unroll
        for (int g = 0; g < NG; ++g) {
            const float xg = xf[g];
            const f32x2 q02 = (f32x2){xg, xg} * (f32x2){xg, xf[TAB.s2[g]]};
            const float q1 = xg * xf[TAB.s1[g]];
            #pragma unroll
            for (int h = 0; h < NG; ++h) {
                const float v = xf[TAB.cay[g][h]];   // static register index
                tau02[h] = __builtin_elementwise_fma((f32x2){v, v}, q02, tau02[h]);
            }
            #pragma unroll
            for (int r = 0; r < 12; ++r) {
                const float v = xf[TAB.cay[g][TAB.rep[r]]];   // static register index
                tau1[r] = fmaf(q1, v, tau1[r]);
            }
        }
        // feature = log2(1 + max(tau,0))  [ln2 folded into W; log2(1)=0 exact]
        uint32_t pk[FPC / 2];
        #pragma unroll
        for (int i = 0; i < 12; ++i) {        // f 0..23: tau0
            float a = __log2f(1.f + fmaxf(tau02[2*i][0],   0.f));
            float b = __log2f(1.f + fmaxf(tau02[2*i+1][0], 0.f));
            pk[i] = f2bf(a) | (f2bf(b) << 16);
        }
        #pragma unroll
        for (int i = 0; i < 6; ++i) {         // f 24..35: tau1 reps
            float a = __log2f(1.f + fmaxf(tau1[2*i],   0.f));
            float b = __log2f(1.f + fmaxf(tau1[2*i+1], 0.f));
            pk[12 + i] = f2bf(a) | (f2bf(b) << 16);
        }
        #pragma unroll
        for (int i = 0; i < 12; ++i) {        // f 36..59: tau2
            float a = __log2f(1.f + fmaxf(tau02[2*i][1],   0.f));
            float b = __log2f(1.f + fmaxf(tau02[2*i+1][1], 0.f));
            pk[18 + i] = f2bf(a) | (f2bf(b) << 16);
        }
        pk[30] = 0u; pk[31] = 0u;             // f 60..63: pad (W' columns are zero)
        // row: p0*2064B (16B-aligned) + cl*128B (16B-aligned) -> 8 x b128 stores
        uint32_t* dst = (uint32_t*)&featS[p0 * KPE + cl * FPC];
        #pragma unroll
        for (int i = 0; i < FPC / 2; i += 4) {
            u32x4 v; v[0] = pk[i]; v[1] = pk[i+1]; v[2] = pk[i+2]; v[3] = pk[i+3];
            *(u32x4*)(dst + i) = v;
        }
    }
    __syncthreads();

    // ---- phase B: wave w accumulates k-steps [8w, 8w+8) for ALL 4 o-tiles ----
    {
        const unsigned kb = (unsigned)(stage * KPSTG + w * KQ);   // global k-step
        const unsigned short* fb = &featS[ln * KPE + (w * KQ) * 32 + lh * 8];
        const s16x8* wb = (const s16x8*)WbS;

        s16x8 bc = *(const s16x8*)(fb);          // b prefetch (shared by 4 o-tiles)
        #pragma unroll
        for (int kk = 0; kk < KQ; ++kk) {
            s16x8 bn = bc;
            if (kk + 1 < KQ) bn = *(const s16x8*)(fb + (kk + 1) * 32);
            const unsigned ai = (kb + (unsigned)kk) * 64u + (unsigned)l;
            s16x8 a0 = wb[ai];
            s16x8 a1 = wb[ai + 1u * KS2 * 64u];
            s16x8 a2 = wb[ai + 2u * KS2 * 64u];
            s16x8 a3 = wb[ai + 3u * KS2 * 64u];
            accA = __builtin_amdgcn_mfma_f32_16x16x32_bf16(a0, bc, accA, 0, 0, 0);
            accB = __builtin_amdgcn_mfma_f32_16x16x32_bf16(a1, bc, accB, 0, 0, 0);
            accC = __builtin_amdgcn_mfma_f32_16x16x32_bf16(a2, bc, accC, 0, 0, 0);
            accD = __builtin_amdgcn_mfma_f32_16x16x32_bf16(a3, bc, accD, 0, 0, 0);
            bc = bn;
        }
    }
    __syncthreads();   // all ds_reads done before redS overlay

    // ---- epilogue: cross-wave k-reduction (featS dead -> overlay), atomic o-tile w ----
    f32x4* redS = (f32x4*)featS;      // 4 waves x 4 o-tiles x 64 lanes x 16B = 16 KB
    redS[(w * 4 + 0) * 64 + l] = accA;
    redS[(w * 4 + 1) * 64 + l] = accB;
    redS[(w * 4 + 2) * 64 + l] = accC;
    redS[(w * 4 + 3) * 64 + l] = accD;
    __syncthreads();
    f32x4 r = redS[(0 * 4 + w) * 64 + l] + redS[(1 * 4 + w) * 64 + l]
            + redS[(2 * 4 + w) * 64 + l] + redS[(3 * 4 + w) * 64 + l];

    // D layout: col = lane&15 (position), row = (lane>>4)*4 + j (head within o-tile w)
    const size_t obase = (size_t)bb * NHEAD * DHW + (size_t)(psp + ln);
    #pragma unroll
    for (int j = 0; j < 4; ++j) {
        const int o = w * 16 + lh * 4 + j;
        atomicAdd(&y[obase + (size_t)o * DHW], r[j]);
    }
}

extern "C" void kernel_launch(void* const* d_in, const int* in_sizes, int n_in,
                              void* d_out, int out_size, void* d_ws, size_t ws_size,
                              hipStream_t stream) {
    const float* x    = (const float*)d_in[0];
    const float* W    = (const float*)d_in[1];
    const float* bias = (const float*)d_in[2];
    unsigned short* WbS = (unsigned short*)d_ws;            // 262,144 B used
    float* y = (float*)d_out;

    init_all<<<dim3(PREPB + FILLB), dim3(256), 0, stream>>>(W, WbS, bias, y);
    bispec_fused<<<dim3(NTILES * 2), dim3(256), 0, stream>>>(x, WbS, y);
}